// Round 4
// baseline (235.280 us; speedup 1.0000x reference)
//
#include <hip/hip_runtime.h>

typedef __attribute__((ext_vector_type(8))) short s8v;       // 8 x bf16 bits
typedef __attribute__((ext_vector_type(4))) float f32x4;
typedef __attribute__((ext_vector_type(4))) unsigned short u16x4;
typedef __attribute__((ext_vector_type(2))) unsigned int u32x2;

#define SEQ 4096
#define DM  768
#define NH  12
#define HD  64

__device__ __forceinline__ unsigned short f2bf(float f) {
  union { float f; unsigned int u; } v; v.f = f;
  unsigned int r = v.u + 0x7fffu + ((v.u >> 16) & 1u);
  return (unsigned short)(r >> 16);
}

__device__ __forceinline__ unsigned int cvtpk(float lo, float hi) {
  unsigned int r;
  asm("v_cvt_pk_bf16_f32 %0, %1, %2" : "=v"(r) : "v"(lo), "v"(hi));
  return r;
}

__device__ __forceinline__ void gload16(const void* g, void* l) {
  __builtin_amdgcn_global_load_lds((const __attribute__((address_space(1))) void*)g,
                                   (__attribute__((address_space(3))) void*)l, 16, 0, 0);
}

// ---------------- elementwise cast fp32 -> bf16 ----------------
__global__ __launch_bounds__(256) void k_cast(const float* __restrict__ in,
                                              unsigned short* __restrict__ out) {
  int i = (blockIdx.x * 256 + threadIdx.x) * 4;
  float4 v = *reinterpret_cast<const float4*>(in + i);
  u16x4 o;
  o.x = f2bf(v.x); o.y = f2bf(v.y); o.z = f2bf(v.z); o.w = f2bf(v.w);
  *reinterpret_cast<u16x4*>(out + i) = o;
}

// ---------------- transpose + cast: in [K][N] f32 -> out [N][K] bf16 ----------------
__global__ __launch_bounds__(256) void k_transpose_cast(const float* __restrict__ in,
                                                        unsigned short* __restrict__ out,
                                                        int K, int N) {
  __shared__ float tile[32][33];
  int k0 = blockIdx.x * 32, n0 = blockIdx.y * 32;
  int tr = threadIdx.x >> 5, tc = threadIdx.x & 31;
#pragma unroll
  for (int i = 0; i < 4; i++)
    tile[i * 8 + tr][tc] = in[(k0 + i * 8 + tr) * N + n0 + tc];
  __syncthreads();
#pragma unroll
  for (int i = 0; i < 4; i++)
    out[(n0 + i * 8 + tr) * K + k0 + tc] = f2bf(tile[tc][i * 8 + tr]);
}

// ---------------- 128x128 bf16 MFMA GEMM, A[M][768] @ BT[N][768]^T ----------------
template<int MODE>
__global__ __launch_bounds__(256) void k_gemm(
    const unsigned short* __restrict__ A, const unsigned short* __restrict__ BT,
    const float* __restrict__ bias,
    unsigned short* __restrict__ Oq, unsigned short* __restrict__ Ok,
    unsigned short* __restrict__ Ov, float* __restrict__ Of) {
  __shared__ unsigned short As[128 * 32];
  __shared__ unsigned short Bs[128 * 32];
  const int tid = threadIdx.x;
  const int lane = tid & 63;
  const int w = tid >> 6;
  const int wm = w >> 1, wn = w & 1;
  const int l15 = lane & 15, l4 = lane >> 4;
  const int m0 = blockIdx.x * 128, n0 = blockIdx.y * 128;

  f32x4 acc[4][4] = {};

  int srow[2], skc[2];
#pragma unroll
  for (int j = 0; j < 2; j++) {
    int slot = j * 256 + tid;
    srow[j] = slot >> 2;
    skc[j] = (slot & 3) ^ ((srow[j] >> 1) & 3);
  }
  const int ldsb0 = (tid & ~63) * 16;
  const int ldsb1 = (256 + (tid & ~63)) * 16;

  for (int k0 = 0; k0 < DM; k0 += 32) {
    gload16(A + (m0 + srow[0]) * DM + k0 + skc[0] * 8, (char*)As + ldsb0);
    gload16(A + (m0 + srow[1]) * DM + k0 + skc[1] * 8, (char*)As + ldsb1);
    gload16(BT + (n0 + srow[0]) * DM + k0 + skc[0] * 8, (char*)Bs + ldsb0);
    gload16(BT + (n0 + srow[1]) * DM + k0 + skc[1] * 8, (char*)Bs + ldsb1);
    __syncthreads();
    s8v af[4], bfr[4];
#pragma unroll
    for (int i = 0; i < 4; i++) {
      int ra = wm * 64 + i * 16 + l15;
      int ca = (l4 ^ ((ra >> 1) & 3)) * 8;
      af[i] = *reinterpret_cast<const s8v*>(&As[ra * 32 + ca]);
      int rb = wn * 64 + i * 16 + l15;
      int cb = (l4 ^ ((rb >> 1) & 3)) * 8;
      bfr[i] = *reinterpret_cast<const s8v*>(&Bs[rb * 32 + cb]);
    }
#pragma unroll
    for (int mi = 0; mi < 4; mi++)
#pragma unroll
      for (int nj = 0; nj < 4; nj++)
        acc[mi][nj] = __builtin_amdgcn_mfma_f32_16x16x32_bf16(af[mi], bfr[nj], acc[mi][nj], 0, 0, 0);
    __syncthreads();
  }

#pragma unroll
  for (int nj = 0; nj < 4; nj++) {
    const int col = n0 + wn * 64 + nj * 16 + l15;
    const float bv = bias[col];
#pragma unroll
    for (int mi = 0; mi < 4; mi++) {
      const int rowb = m0 + wm * 64 + mi * 16 + l4 * 4;
      if (MODE == 0) {
        if (col < 768) {
#pragma unroll
          for (int r = 0; r < 4; r++)
            Oq[(rowb + r) * DM + col] = f2bf(acc[mi][nj][r] + bv);
        } else if (col < 1536) {
#pragma unroll
          for (int r = 0; r < 4; r++)
            Ok[(rowb + r) * DM + (col - 768)] = f2bf(acc[mi][nj][r] + bv);
        } else {
          u16x4 pk;
#pragma unroll
          for (int r = 0; r < 4; r++)
            pk[r] = f2bf(acc[mi][nj][r] + bv);
          *reinterpret_cast<u16x4*>(&Ov[(col - 1536) * SEQ + rowb]) = pk;
        }
      } else {
#pragma unroll
        for (int r = 0; r < 4; r++)
          Of[(rowb + r) * DM + col] = acc[mi][nj][r] + bv;
      }
    }
  }
}

// ---------------- causal flash attention, swapped-operand softmax ----------------
// Block: 16 q-rows of one head; 4 waves key-split (t = w, w+4, ...).
// Swapped QK^T: S^T[key][q], q = lane&15 lane-local -> in-lane softmax.
// Swapped PV: O^T[d][q] accumulator. Merge partials via LDS at the end.
// K/V loads are issued as a burst at iteration top and pinned with keep-alive
// asm so the compiler cannot sink them into the serial chain (round-3 lesson:
// at VGPR=64 it sank every load -> ~4K-cycle serial L3 latency per tile).
__global__ __launch_bounds__(256, 4) void k_attn(
    const unsigned short* __restrict__ Qb, const unsigned short* __restrict__ Kb,
    const unsigned short* __restrict__ Vt, unsigned short* __restrict__ Aout) {
  __shared__ unsigned char Pl[4][2048];  // per-wave P^T buffer (16 q-rows x 64 keys bf16, swizzled)
  __shared__ float Os[4][16][68];        // per-wave O partials [q][d] (+pad)
  __shared__ float Ml[4][2][16];         // per-wave m,l per q-row
  const int tid = threadIdx.x;
  const int lane = tid & 63;
  const int w = tid >> 6;
  const int l15 = lane & 15, l4 = lane >> 4;
  const int bid = blockIdx.x;
  const int h = bid % NH;
  const int qt = 255 - (bid / NH);      // heavy q-tiles dispatch first
  const int q0 = qt * 16;
  const int ntiles = q0 / 64 + 1;
  const float SCL = 0.125f * 1.44269504f;  // (1/sqrt(hd)) * log2(e)

  // Q fragment (B-operand of swapped QK): lane holds Q[q0+l15][kc*32 + l4*8 ..+7]
  s8v aq[2];
#pragma unroll
  for (int kc = 0; kc < 2; kc++)
    aq[kc] = *reinterpret_cast<const s8v*>(&Qb[(q0 + l15) * DM + h * HD + kc * 32 + l4 * 8]);

  // loop-invariant per-lane LDS byte offsets (XOR swizzle by q-row)
  unsigned char* const pw = (unsigned char*)&Pl[w][0];
  const int swz = (l15 & 7) << 4;
  const int wr_base = l15 * 128 + l4 * 8;    // + c2*32, ^ swz
  const int rd_base = l15 * 128 + l4 * 16;   // + kc2*64, ^ swz
  const int lanediff = l15 - l4 * 4;

  const unsigned short* const Kh = Kb + h * HD;
  const unsigned short* const Vh = Vt + h * HD * SEQ;

  f32x4 Ot[4] = {};                          // Ot[dc][r] = O[q=l15][d = dc*16 + l4*4 + r]
  float m = -1e30f, lsum = 0.f;

  for (int t = w; t < ntiles; t += 4) {
    const int kb = t * 64;
    // ---- issue burst: 8 K loads then 8 V loads, all in flight together ----
    s8v bk[4][2];
#pragma unroll
    for (int c2 = 0; c2 < 4; c2++)
#pragma unroll
      for (int kc = 0; kc < 2; kc++)
        bk[c2][kc] = *reinterpret_cast<const s8v*>(
            &Kh[(kb + c2 * 16 + l15) * DM + kc * 32 + l4 * 8]);
    s8v av[4][2];
#pragma unroll
    for (int dc = 0; dc < 4; dc++)
#pragma unroll
      for (int kc2 = 0; kc2 < 2; kc2++)
        av[dc][kc2] = *reinterpret_cast<const s8v*>(
            &Vh[(dc * 16 + l15) * SEQ + kb + kc2 * 32 + l4 * 8]);
    // pin K in registers here (single burst wait; V stays in flight)
    asm volatile("" :: "v"(bk[0][0]), "v"(bk[0][1]), "v"(bk[1][0]), "v"(bk[1][1]),
                       "v"(bk[2][0]), "v"(bk[2][1]), "v"(bk[3][0]), "v"(bk[3][1]));

    // swapped QK^T: raw scores, key = kb + c2*16 + l4*4 + r, q = q0 + l15
    float p[4][4];
#pragma unroll
    for (int c2 = 0; c2 < 4; c2++) {
      f32x4 z = {};
      z = __builtin_amdgcn_mfma_f32_16x16x32_bf16(bk[c2][0], aq[0], z, 0, 0, 0);
      z = __builtin_amdgcn_mfma_f32_16x16x32_bf16(bk[c2][1], aq[1], z, 0, 0, 0);
#pragma unroll
      for (int r = 0; r < 4; r++) p[c2][r] = z[r];
    }
    // pin V in registers before softmax (landed under K-wait + QK MFMAs)
    asm volatile("" :: "v"(av[0][0]), "v"(av[0][1]), "v"(av[1][0]), "v"(av[1][1]),
                       "v"(av[2][0]), "v"(av[2][1]), "v"(av[3][0]), "v"(av[3][1]));

    // causal mask: only the diagonal tile needs it (wave-uniform branch)
    if (kb + 63 > q0) {
      const int qml = q0 - kb + lanediff;   // mask if c2*16 + r > qml
#pragma unroll
      for (int c2 = 0; c2 < 4; c2++)
#pragma unroll
        for (int r = 0; r < 4; r++)
          p[c2][r] = (c2 * 16 + r > qml) ? -1e30f : p[c2][r];
    }
    // in-lane max tree (16 values) + cross-l4 reduce (2 shuffles)
    float t0 = fmaxf(fmaxf(p[0][0], p[0][1]), fmaxf(p[0][2], p[0][3]));
    float t1 = fmaxf(fmaxf(p[1][0], p[1][1]), fmaxf(p[1][2], p[1][3]));
    float t2 = fmaxf(fmaxf(p[2][0], p[2][1]), fmaxf(p[2][2], p[2][3]));
    float t3 = fmaxf(fmaxf(p[3][0], p[3][1]), fmaxf(p[3][2], p[3][3]));
    float tm = fmaxf(fmaxf(t0, t1), fmaxf(t2, t3));
    tm = fmaxf(tm, __shfl_xor(tm, 16));
    tm = fmaxf(tm, __shfl_xor(tm, 32));
    const float tsc = tm * SCL;
    // defer-max (T13): rescale only when tile max exceeds running max by >8 (log2)
    if (!__all(tsc <= m + 8.f)) {
      const float mn = fmaxf(m, tsc);
      const float al = exp2f(m - mn);
      m = mn;
      lsum *= al;
#pragma unroll
      for (int dc = 0; dc < 4; dc++)
#pragma unroll
        for (int r = 0; r < 4; r++) Ot[dc][r] *= al;
    }
    // exp (log2 domain), pack to bf16 pairs, write P^T row q=l15 to LDS
    float s = 0.f;
#pragma unroll
    for (int c2 = 0; c2 < 4; c2++) {
      float e0 = exp2f(fmaf(p[c2][0], SCL, -m));
      float e1 = exp2f(fmaf(p[c2][1], SCL, -m));
      float e2 = exp2f(fmaf(p[c2][2], SCL, -m));
      float e3 = exp2f(fmaf(p[c2][3], SCL, -m));
      s += (e0 + e1) + (e2 + e3);
      u32x2 pk;
      pk.x = cvtpk(e0, e1);
      pk.y = cvtpk(e2, e3);
      *reinterpret_cast<u32x2*>(pw + ((wr_base + c2 * 32) ^ swz)) = pk;
    }
    lsum += s;
    __asm__ volatile("s_waitcnt lgkmcnt(0)" ::: "memory");
    const s8v pb0 = *reinterpret_cast<const s8v*>(pw + ((rd_base) ^ swz));
    const s8v pb1 = *reinterpret_cast<const s8v*>(pw + ((rd_base + 64) ^ swz));
#pragma unroll
    for (int dc = 0; dc < 4; dc++) {
      Ot[dc] = __builtin_amdgcn_mfma_f32_16x16x32_bf16(av[dc][0], pb0, Ot[dc], 0, 0, 0);
      Ot[dc] = __builtin_amdgcn_mfma_f32_16x16x32_bf16(av[dc][1], pb1, Ot[dc], 0, 0, 0);
    }
  }

  // ---- publish per-wave state ----
  lsum += __shfl_xor(lsum, 16);
  lsum += __shfl_xor(lsum, 32);
#pragma unroll
  for (int dc = 0; dc < 4; dc++)
    *reinterpret_cast<f32x4*>(&Os[w][l15][dc * 16 + l4 * 4]) = Ot[dc];
  if (l4 == 0) {
    Ml[w][0][l15] = m;
    Ml[w][1][l15] = lsum;
  }
  __syncthreads();

  // ---- merge 4 partials; wave w writes output d-cols [w*16, w*16+16) ----
#pragma unroll
  for (int r = 0; r < 4; r++) {
    const int row = l4 * 4 + r;   // q-row
    float m0 = Ml[0][0][row], m1 = Ml[1][0][row], m2 = Ml[2][0][row], m3 = Ml[3][0][row];
    float ms = fmaxf(fmaxf(m0, m1), fmaxf(m2, m3));
    float s0 = exp2f(m0 - ms), s1 = exp2f(m1 - ms), s2 = exp2f(m2 - ms), s3 = exp2f(m3 - ms);
    float lsum4 = s0 * Ml[0][1][row] + s1 * Ml[1][1][row] + s2 * Ml[2][1][row] + s3 * Ml[3][1][row];
    float acc = s0 * Os[0][row][w * 16 + l15] + s1 * Os[1][row][w * 16 + l15] +
                s2 * Os[2][row][w * 16 + l15] + s3 * Os[3][row][w * 16 + l15];
    Aout[(q0 + row) * DM + h * HD + w * 16 + l15] = f2bf(acc / lsum4);
  }
}

extern "C" void kernel_launch(void* const* d_in, const int* in_sizes, int n_in,
                              void* d_out, int out_size, void* d_ws, size_t ws_size,
                              hipStream_t stream) {
  (void)in_sizes; (void)n_in; (void)out_size; (void)ws_size;
  const float* tokens = (const float*)d_in[0];
  const float* wqkv  = (const float*)d_in[2];
  const float* bqkv  = (const float*)d_in[3];
  const float* wproj = (const float*)d_in[4];
  const float* bproj = (const float*)d_in[5];
  float* out = (float*)d_out;

  unsigned short* tok    = (unsigned short*)d_ws;       // [4096][768]
  unsigned short* wqkvT  = tok + 4096 * 768;            // [2304][768]
  unsigned short* wprojT = wqkvT + 2304 * 768;          // [768][768]
  unsigned short* Qb     = wprojT + 768 * 768;          // [4096][768]
  unsigned short* Kb     = Qb + 4096 * 768;             // [4096][768]
  unsigned short* Vt     = Kb + 4096 * 768;             // [768][4096]
  unsigned short* attn   = Vt + 768 * 4096;             // [4096][768]

  k_cast<<<3072, 256, 0, stream>>>(tokens, tok);
  k_transpose_cast<<<dim3(24, 72), 256, 0, stream>>>(wqkv, wqkvT, 768, 2304);
  k_transpose_cast<<<dim3(24, 24), 256, 0, stream>>>(wproj, wprojT, 768, 768);
  k_gemm<0><<<dim3(32, 18), 256, 0, stream>>>(tok, wqkvT, bqkv, Qb, Kb, Vt, nullptr);
  k_attn<<<3072, 256, 0, stream>>>(Qb, Kb, Vt, attn);
  k_gemm<1><<<dim3(32, 6), 256, 0, stream>>>(attn, wprojT, bproj, nullptr, nullptr, nullptr, out);
}

// Round 5
// 137.683 us; speedup vs baseline: 1.7088x; 1.7088x over previous
//
#include <hip/hip_runtime.h>

typedef __attribute__((ext_vector_type(8))) short s8v;       // 8 x bf16 bits
typedef __attribute__((ext_vector_type(4))) float f32x4;
typedef __attribute__((ext_vector_type(4))) unsigned short u16x4;
typedef __attribute__((ext_vector_type(2))) unsigned int u32x2;

#define SEQ 4096
#define DM  768
#define NH  12
#define HD  64

__device__ __forceinline__ unsigned short f2bf(float f) {
  union { float f; unsigned int u; } v; v.f = f;
  unsigned int r = v.u + 0x7fffu + ((v.u >> 16) & 1u);
  return (unsigned short)(r >> 16);
}

__device__ __forceinline__ unsigned int cvtpk(float lo, float hi) {
  unsigned int r;
  asm("v_cvt_pk_bf16_f32 %0, %1, %2" : "=v"(r) : "v"(lo), "v"(hi));
  return r;
}

__device__ __forceinline__ void gload16(const void* g, void* l) {
  __builtin_amdgcn_global_load_lds((const __attribute__((address_space(1))) void*)g,
                                   (__attribute__((address_space(3))) void*)l, 16, 0, 0);
}

// ---------------- elementwise cast fp32 -> bf16 ----------------
__global__ __launch_bounds__(256) void k_cast(const float* __restrict__ in,
                                              unsigned short* __restrict__ out) {
  int i = (blockIdx.x * 256 + threadIdx.x) * 4;
  float4 v = *reinterpret_cast<const float4*>(in + i);
  u16x4 o;
  o.x = f2bf(v.x); o.y = f2bf(v.y); o.z = f2bf(v.z); o.w = f2bf(v.w);
  *reinterpret_cast<u16x4*>(out + i) = o;
}

// ---------------- transpose + cast: in [K][N] f32 -> out [N][K] bf16 ----------------
__global__ __launch_bounds__(256) void k_transpose_cast(const float* __restrict__ in,
                                                        unsigned short* __restrict__ out,
                                                        int K, int N) {
  __shared__ float tile[32][33];
  int k0 = blockIdx.x * 32, n0 = blockIdx.y * 32;
  int tr = threadIdx.x >> 5, tc = threadIdx.x & 31;
#pragma unroll
  for (int i = 0; i < 4; i++)
    tile[i * 8 + tr][tc] = in[(k0 + i * 8 + tr) * N + n0 + tc];
  __syncthreads();
#pragma unroll
  for (int i = 0; i < 4; i++)
    out[(n0 + i * 8 + tr) * K + k0 + tc] = f2bf(tile[tc][i * 8 + tr]);
}

// ---------------- 128x128 bf16 MFMA GEMM, A[M][768] @ BT[N][768]^T ----------------
template<int MODE>
__global__ __launch_bounds__(256) void k_gemm(
    const unsigned short* __restrict__ A, const unsigned short* __restrict__ BT,
    const float* __restrict__ bias,
    unsigned short* __restrict__ Oq, unsigned short* __restrict__ Ok,
    unsigned short* __restrict__ Ov, float* __restrict__ Of) {
  __shared__ unsigned short As[128 * 32];
  __shared__ unsigned short Bs[128 * 32];
  const int tid = threadIdx.x;
  const int lane = tid & 63;
  const int w = tid >> 6;
  const int wm = w >> 1, wn = w & 1;
  const int l15 = lane & 15, l4 = lane >> 4;
  const int m0 = blockIdx.x * 128, n0 = blockIdx.y * 128;

  f32x4 acc[4][4] = {};

  int srow[2], skc[2];
#pragma unroll
  for (int j = 0; j < 2; j++) {
    int slot = j * 256 + tid;
    srow[j] = slot >> 2;
    skc[j] = (slot & 3) ^ ((srow[j] >> 1) & 3);
  }
  const int ldsb0 = (tid & ~63) * 16;
  const int ldsb1 = (256 + (tid & ~63)) * 16;

  for (int k0 = 0; k0 < DM; k0 += 32) {
    gload16(A + (m0 + srow[0]) * DM + k0 + skc[0] * 8, (char*)As + ldsb0);
    gload16(A + (m0 + srow[1]) * DM + k0 + skc[1] * 8, (char*)As + ldsb1);
    gload16(BT + (n0 + srow[0]) * DM + k0 + skc[0] * 8, (char*)Bs + ldsb0);
    gload16(BT + (n0 + srow[1]) * DM + k0 + skc[1] * 8, (char*)Bs + ldsb1);
    __syncthreads();
    s8v af[4], bfr[4];
#pragma unroll
    for (int i = 0; i < 4; i++) {
      int ra = wm * 64 + i * 16 + l15;
      int ca = (l4 ^ ((ra >> 1) & 3)) * 8;
      af[i] = *reinterpret_cast<const s8v*>(&As[ra * 32 + ca]);
      int rb = wn * 64 + i * 16 + l15;
      int cb = (l4 ^ ((rb >> 1) & 3)) * 8;
      bfr[i] = *reinterpret_cast<const s8v*>(&Bs[rb * 32 + cb]);
    }
#pragma unroll
    for (int mi = 0; mi < 4; mi++)
#pragma unroll
      for (int nj = 0; nj < 4; nj++)
        acc[mi][nj] = __builtin_amdgcn_mfma_f32_16x16x32_bf16(af[mi], bfr[nj], acc[mi][nj], 0, 0, 0);
    __syncthreads();
  }

#pragma unroll
  for (int nj = 0; nj < 4; nj++) {
    const int col = n0 + wn * 64 + nj * 16 + l15;
    const float bv = bias[col];
#pragma unroll
    for (int mi = 0; mi < 4; mi++) {
      const int rowb = m0 + wm * 64 + mi * 16 + l4 * 4;
      if (MODE == 0) {
        if (col < 768) {
#pragma unroll
          for (int r = 0; r < 4; r++)
            Oq[(rowb + r) * DM + col] = f2bf(acc[mi][nj][r] + bv);
        } else if (col < 1536) {
#pragma unroll
          for (int r = 0; r < 4; r++)
            Ok[(rowb + r) * DM + (col - 768)] = f2bf(acc[mi][nj][r] + bv);
        } else {
          u16x4 pk;
#pragma unroll
          for (int r = 0; r < 4; r++)
            pk[r] = f2bf(acc[mi][nj][r] + bv);
          *reinterpret_cast<u16x4*>(&Ov[(col - 1536) * SEQ + rowb]) = pk;
        }
      } else {
#pragma unroll
        for (int r = 0; r < 4; r++)
          Of[(rowb + r) * DM + col] = acc[mi][nj][r] + bv;
      }
    }
  }
}

// ---------------- causal flash attention, cooperative LDS-staged K/V ----------------
// Block: 64 q-rows x 1 head; 4 waves each own 16 q-rows and SHARE the staged
// K/V tile (64 keys). 2-phase async pipeline: stage(t+1) via global_load_lds
// -> compute(t) from LDS -> vmcnt(0)+barrier. Load latency hides structurally
// (rounds 3-4 lesson: compiler refuses register-resident prefetch at source).
// K staged [key][d], V staged [d][key]; both XOR slot-swizzled (slot ^= row&7),
// applied on the GLOBAL source (linear LDS dest, rule 21) and on the LDS read.
__global__ __launch_bounds__(256, 3) void k_attn(
    const unsigned short* __restrict__ Qb, const unsigned short* __restrict__ Kb,
    const unsigned short* __restrict__ Vt, unsigned short* __restrict__ Aout) {
  __shared__ unsigned short Ks[2][64 * 64];   // [key][d], swizzled, 8KB each
  __shared__ unsigned short Vs[2][64 * 64];   // [d][key], swizzled, 8KB each
  __shared__ unsigned char Pl[4][2048];       // per-wave P^T (16 q x 64 k bf16, swizzled)
  const int tid = threadIdx.x;
  const int lane = tid & 63;
  const int w = tid >> 6;
  const int l15 = lane & 15, l4 = lane >> 4;
  const int bid = blockIdx.x;
  const int h = bid % NH;
  const int qt = 63 - (bid / NH);        // heavy q-tiles dispatch first
  const int q0 = qt * 64 + w * 16;       // this wave's first q-row
  const int ntiles = qt + 1;
  const float SCL = 0.125f * 1.44269504f;  // (1/sqrt(hd)) * log2(e)

  const unsigned short* const Kh = Kb + h * HD;
  const unsigned short* const Vh = Vt + h * HD * SEQ;

  // staging: 512 chunks of 16B per matrix; chunk c: row rr=c>>3, lds slot s=c&7
  // holds global slot s ^ (rr&7). Linear LDS dest (wave base + lane*16).
  int srow[2], scol[2];
#pragma unroll
  for (int j = 0; j < 2; j++) {
    int c = j * 256 + tid;
    srow[j] = c >> 3;
    scol[j] = ((c & 7) ^ (srow[j] & 7)) * 8;   // element offset within 64-wide row
  }
  const int ldsoff0 = (tid & ~63) * 16;         // j=0 wave-uniform byte base
  const int ldsoff1 = 4096 + (tid & ~63) * 16;  // j=1

  // Q fragment (B-operand of swapped QK): lane holds Q[q0+l15][kc*32 + l4*8 ..+7]
  s8v aq[2];
#pragma unroll
  for (int kc = 0; kc < 2; kc++)
    aq[kc] = *reinterpret_cast<const s8v*>(&Qb[(q0 + l15) * DM + h * HD + kc * 32 + l4 * 8]);

  // LDS read bases: row rr, global slot g -> byte rr*128 + ((g ^ (rr&7))<<4).
  // K frag (c2,kc): rr=c2*16+l15, g=kc*4+l4;  V frag (dc,kc2): same shape.
  const int kvbase = l15 * 128 + ((l4 ^ (l15 & 7)) << 4);  // + c2*2048, ^64 for 2nd half

  // P-LDS per-lane offsets (XOR swizzle by q-row)
  unsigned char* const pw = (unsigned char*)&Pl[w][0];
  const int swz = (l15 & 7) << 4;
  const int wr_base = l15 * 128 + l4 * 8;    // + c2*32, ^ swz
  const int rd_base = l15 * 128 + l4 * 16;   // + kc2*64, ^ swz
  const int lanediff = l15 - l4 * 4;

  // ---- prologue: stage tile 0 into buffer 0 ----
  gload16(Kh + srow[0] * DM + scol[0], (char*)Ks[0] + ldsoff0);
  gload16(Kh + srow[1] * DM + scol[1], (char*)Ks[0] + ldsoff1);
  gload16(Vh + srow[0] * SEQ + scol[0], (char*)Vs[0] + ldsoff0);
  gload16(Vh + srow[1] * SEQ + scol[1], (char*)Vs[0] + ldsoff1);
  __asm__ volatile("s_waitcnt vmcnt(0)" ::: "memory");
  __syncthreads();

  f32x4 Ot[4] = {};                          // Ot[dc][r] = O[q=l15][d=dc*16+l4*4+r]
  float m = -1e30f, lsum = 0.f;

  for (int t = 0; t < ntiles; t++) {
    const int cur = t & 1;
    // ---- stage next tile (async, no VGPR cost) ----
    if (t + 1 < ntiles) {
      const int kb2 = (t + 1) * 64;
      const int nxt = cur ^ 1;
      gload16(Kh + (kb2 + srow[0]) * DM + scol[0], (char*)Ks[nxt] + ldsoff0);
      gload16(Kh + (kb2 + srow[1]) * DM + scol[1], (char*)Ks[nxt] + ldsoff1);
      gload16(Vh + srow[0] * SEQ + kb2 + scol[0], (char*)Vs[nxt] + ldsoff0);
      gload16(Vh + srow[1] * SEQ + kb2 + scol[1], (char*)Vs[nxt] + ldsoff1);
    }
    const int kb = t * 64;
    const char* const kbuf = (const char*)Ks[cur];
    const char* const vbuf = (const char*)Vs[cur];

    // ---- swapped QK^T from LDS: key = kb + c2*16 + l4*4 + r, q = q0 + l15 ----
    float p[4][4];
#pragma unroll
    for (int c2 = 0; c2 < 4; c2++) {
      const s8v k0 = *reinterpret_cast<const s8v*>(kbuf + (c2 * 2048 + kvbase));
      const s8v k1 = *reinterpret_cast<const s8v*>(kbuf + ((c2 * 2048 + kvbase) ^ 64));
      f32x4 z = {};
      z = __builtin_amdgcn_mfma_f32_16x16x32_bf16(k0, aq[0], z, 0, 0, 0);
      z = __builtin_amdgcn_mfma_f32_16x16x32_bf16(k1, aq[1], z, 0, 0, 0);
#pragma unroll
      for (int r = 0; r < 4; r++) p[c2][r] = z[r];
    }
    // causal mask: only the wave's diagonal tile (wave-uniform branch)
    if (kb + 63 > q0) {
      const int qml = q0 - kb + lanediff;   // mask if c2*16 + r > qml
#pragma unroll
      for (int c2 = 0; c2 < 4; c2++)
#pragma unroll
        for (int r = 0; r < 4; r++)
          p[c2][r] = (c2 * 16 + r > qml) ? -1e30f : p[c2][r];
    }
    // ---- in-lane softmax (log2 domain), 2 shuffles per tile ----
    float t0 = fmaxf(fmaxf(p[0][0], p[0][1]), fmaxf(p[0][2], p[0][3]));
    float t1 = fmaxf(fmaxf(p[1][0], p[1][1]), fmaxf(p[1][2], p[1][3]));
    float t2 = fmaxf(fmaxf(p[2][0], p[2][1]), fmaxf(p[2][2], p[2][3]));
    float t3 = fmaxf(fmaxf(p[3][0], p[3][1]), fmaxf(p[3][2], p[3][3]));
    float tm = fmaxf(fmaxf(t0, t1), fmaxf(t2, t3));
    tm = fmaxf(tm, __shfl_xor(tm, 16));
    tm = fmaxf(tm, __shfl_xor(tm, 32));
    const float tsc = tm * SCL;
    // defer-max (T13): rescale only when tile max exceeds running max by >8
    if (!__all(tsc <= m + 8.f)) {
      const float mn = fmaxf(m, tsc);
      const float al = exp2f(m - mn);
      m = mn;
      lsum *= al;
#pragma unroll
      for (int dc = 0; dc < 4; dc++)
#pragma unroll
        for (int r = 0; r < 4; r++) Ot[dc][r] *= al;
    }
    // ---- exp, pack bf16, P^T -> LDS ----
    float s = 0.f;
#pragma unroll
    for (int c2 = 0; c2 < 4; c2++) {
      float e0 = exp2f(fmaf(p[c2][0], SCL, -m));
      float e1 = exp2f(fmaf(p[c2][1], SCL, -m));
      float e2 = exp2f(fmaf(p[c2][2], SCL, -m));
      float e3 = exp2f(fmaf(p[c2][3], SCL, -m));
      s += (e0 + e1) + (e2 + e3);
      u32x2 pk;
      pk.x = cvtpk(e0, e1);
      pk.y = cvtpk(e2, e3);
      *reinterpret_cast<u32x2*>(pw + ((wr_base + c2 * 32) ^ swz)) = pk;
    }
    lsum += s;
    __asm__ volatile("s_waitcnt lgkmcnt(0)" ::: "memory");
    const s8v pb0 = *reinterpret_cast<const s8v*>(pw + (rd_base ^ swz));
    const s8v pb1 = *reinterpret_cast<const s8v*>(pw + ((rd_base + 64) ^ swz));
    // ---- swapped PV from LDS V^T ----
#pragma unroll
    for (int dc = 0; dc < 4; dc++) {
      const s8v v0 = *reinterpret_cast<const s8v*>(vbuf + (dc * 2048 + kvbase));
      const s8v v1 = *reinterpret_cast<const s8v*>(vbuf + ((dc * 2048 + kvbase) ^ 64));
      Ot[dc] = __builtin_amdgcn_mfma_f32_16x16x32_bf16(v0, pb0, Ot[dc], 0, 0, 0);
      Ot[dc] = __builtin_amdgcn_mfma_f32_16x16x32_bf16(v1, pb1, Ot[dc], 0, 0, 0);
    }
    // ---- next tile staged & everyone done reading cur ----
    __asm__ volatile("s_waitcnt vmcnt(0)" ::: "memory");
    __syncthreads();
  }

  // ---- finalize: wave owns its 16 q-rows; write directly ----
  lsum += __shfl_xor(lsum, 16);
  lsum += __shfl_xor(lsum, 32);
  const float rl = 1.f / lsum;
#pragma unroll
  for (int dc = 0; dc < 4; dc++) {
    u16x4 pk;
#pragma unroll
    for (int r = 0; r < 4; r++) pk[r] = f2bf(Ot[dc][r] * rl);
    *reinterpret_cast<u16x4*>(&Aout[(q0 + l15) * DM + h * HD + dc * 16 + l4 * 4]) = pk;
  }
}

extern "C" void kernel_launch(void* const* d_in, const int* in_sizes, int n_in,
                              void* d_out, int out_size, void* d_ws, size_t ws_size,
                              hipStream_t stream) {
  (void)in_sizes; (void)n_in; (void)out_size; (void)ws_size;
  const float* tokens = (const float*)d_in[0];
  const float* wqkv  = (const float*)d_in[2];
  const float* bqkv  = (const float*)d_in[3];
  const float* wproj = (const float*)d_in[4];
  const float* bproj = (const float*)d_in[5];
  float* out = (float*)d_out;

  unsigned short* tok    = (unsigned short*)d_ws;       // [4096][768]
  unsigned short* wqkvT  = tok + 4096 * 768;            // [2304][768]
  unsigned short* wprojT = wqkvT + 2304 * 768;          // [768][768]
  unsigned short* Qb     = wprojT + 768 * 768;          // [4096][768]
  unsigned short* Kb     = Qb + 4096 * 768;             // [4096][768]
  unsigned short* Vt     = Kb + 4096 * 768;             // [768][4096]
  unsigned short* attn   = Vt + 768 * 4096;             // [4096][768]

  k_cast<<<3072, 256, 0, stream>>>(tokens, tok);
  k_transpose_cast<<<dim3(24, 72), 256, 0, stream>>>(wqkv, wqkvT, 768, 2304);
  k_transpose_cast<<<dim3(24, 24), 256, 0, stream>>>(wproj, wprojT, 768, 768);
  k_gemm<0><<<dim3(32, 18), 256, 0, stream>>>(tok, wqkvT, bqkv, Qb, Kb, Vt, nullptr);
  k_attn<<<768, 256, 0, stream>>>(Qb, Kb, Vt, attn);
  k_gemm<1><<<dim3(32, 6), 256, 0, stream>>>(attn, wprojT, bproj, nullptr, nullptr, nullptr, out);
}

// Round 6
// 119.112 us; speedup vs baseline: 1.9753x; 1.1559x over previous
//
#include <hip/hip_runtime.h>

typedef __attribute__((ext_vector_type(8))) short s8v;       // 8 x bf16 bits
typedef __attribute__((ext_vector_type(4))) float f32x4;
typedef __attribute__((ext_vector_type(4))) unsigned short u16x4;
typedef __attribute__((ext_vector_type(2))) unsigned int u32x2;

#define SEQ 4096
#define DM  768
#define NH  12
#define HD  64

__device__ __forceinline__ unsigned short f2bf(float f) {
  union { float f; unsigned int u; } v; v.f = f;
  unsigned int r = v.u + 0x7fffu + ((v.u >> 16) & 1u);
  return (unsigned short)(r >> 16);
}

__device__ __forceinline__ unsigned int cvtpk(float lo, float hi) {
  unsigned int r;
  asm("v_cvt_pk_bf16_f32 %0, %1, %2" : "=v"(r) : "v"(lo), "v"(hi));
  return r;
}

__device__ __forceinline__ void gload16(const void* g, void* l) {
  __builtin_amdgcn_global_load_lds((const __attribute__((address_space(1))) void*)g,
                                   (__attribute__((address_space(3))) void*)l, 16, 0, 0);
}

// ---------------- elementwise cast fp32 -> bf16 ----------------
__global__ __launch_bounds__(256) void k_cast(const float* __restrict__ in,
                                              unsigned short* __restrict__ out) {
  int i = (blockIdx.x * 256 + threadIdx.x) * 4;
  float4 v = *reinterpret_cast<const float4*>(in + i);
  u16x4 o;
  o.x = f2bf(v.x); o.y = f2bf(v.y); o.z = f2bf(v.z); o.w = f2bf(v.w);
  *reinterpret_cast<u16x4*>(out + i) = o;
}

// ---------------- transpose + cast: in [K][N] f32 -> out [N][K] bf16 ----------------
__global__ __launch_bounds__(256) void k_transpose_cast(const float* __restrict__ in,
                                                        unsigned short* __restrict__ out,
                                                        int K, int N) {
  __shared__ float tile[32][33];
  int k0 = blockIdx.x * 32, n0 = blockIdx.y * 32;
  int tr = threadIdx.x >> 5, tc = threadIdx.x & 31;
#pragma unroll
  for (int i = 0; i < 4; i++)
    tile[i * 8 + tr][tc] = in[(k0 + i * 8 + tr) * N + n0 + tc];
  __syncthreads();
#pragma unroll
  for (int i = 0; i < 4; i++)
    out[(n0 + i * 8 + tr) * K + k0 + tc] = f2bf(tile[tc][i * 8 + tr]);
}

// ---------------- 128x128 bf16 MFMA GEMM, A[M][768] @ BT[N][768]^T ----------------
template<int MODE>
__global__ __launch_bounds__(256) void k_gemm(
    const unsigned short* __restrict__ A, const unsigned short* __restrict__ BT,
    const float* __restrict__ bias,
    unsigned short* __restrict__ Oq, unsigned short* __restrict__ Ok,
    unsigned short* __restrict__ Ov, float* __restrict__ Of) {
  __shared__ unsigned short As[128 * 32];
  __shared__ unsigned short Bs[128 * 32];
  const int tid = threadIdx.x;
  const int lane = tid & 63;
  const int w = tid >> 6;
  const int wm = w >> 1, wn = w & 1;
  const int l15 = lane & 15, l4 = lane >> 4;
  const int m0 = blockIdx.x * 128, n0 = blockIdx.y * 128;

  f32x4 acc[4][4] = {};

  int srow[2], skc[2];
#pragma unroll
  for (int j = 0; j < 2; j++) {
    int slot = j * 256 + tid;
    srow[j] = slot >> 2;
    skc[j] = (slot & 3) ^ ((srow[j] >> 1) & 3);
  }
  const int ldsb0 = (tid & ~63) * 16;
  const int ldsb1 = (256 + (tid & ~63)) * 16;

  for (int k0 = 0; k0 < DM; k0 += 32) {
    gload16(A + (m0 + srow[0]) * DM + k0 + skc[0] * 8, (char*)As + ldsb0);
    gload16(A + (m0 + srow[1]) * DM + k0 + skc[1] * 8, (char*)As + ldsb1);
    gload16(BT + (n0 + srow[0]) * DM + k0 + skc[0] * 8, (char*)Bs + ldsb0);
    gload16(BT + (n0 + srow[1]) * DM + k0 + skc[1] * 8, (char*)Bs + ldsb1);
    __syncthreads();
    s8v af[4], bfr[4];
#pragma unroll
    for (int i = 0; i < 4; i++) {
      int ra = wm * 64 + i * 16 + l15;
      int ca = (l4 ^ ((ra >> 1) & 3)) * 8;
      af[i] = *reinterpret_cast<const s8v*>(&As[ra * 32 + ca]);
      int rb = wn * 64 + i * 16 + l15;
      int cb = (l4 ^ ((rb >> 1) & 3)) * 8;
      bfr[i] = *reinterpret_cast<const s8v*>(&Bs[rb * 32 + cb]);
    }
#pragma unroll
    for (int mi = 0; mi < 4; mi++)
#pragma unroll
      for (int nj = 0; nj < 4; nj++)
        acc[mi][nj] = __builtin_amdgcn_mfma_f32_16x16x32_bf16(af[mi], bfr[nj], acc[mi][nj], 0, 0, 0);
    __syncthreads();
  }

#pragma unroll
  for (int nj = 0; nj < 4; nj++) {
    const int col = n0 + wn * 64 + nj * 16 + l15;
    const float bv = bias[col];
#pragma unroll
    for (int mi = 0; mi < 4; mi++) {
      const int rowb = m0 + wm * 64 + mi * 16 + l4 * 4;
      if (MODE == 0) {
        if (col < 768) {
#pragma unroll
          for (int r = 0; r < 4; r++)
            Oq[(rowb + r) * DM + col] = f2bf(acc[mi][nj][r] + bv);
        } else if (col < 1536) {
#pragma unroll
          for (int r = 0; r < 4; r++)
            Ok[(rowb + r) * DM + (col - 768)] = f2bf(acc[mi][nj][r] + bv);
        } else {
          u16x4 pk;
#pragma unroll
          for (int r = 0; r < 4; r++)
            pk[r] = f2bf(acc[mi][nj][r] + bv);
          *reinterpret_cast<u16x4*>(&Ov[(col - 1536) * SEQ + rowb]) = pk;
        }
      } else {
#pragma unroll
        for (int r = 0; r < 4; r++)
          Of[(rowb + r) * DM + col] = acc[mi][nj][r] + bv;
      }
    }
  }
}

// ---------------- causal flash attention, LDS-staged K/V, 2-way key-split ----------------
// Block (qt,h,s): 64 q-rows of head h, key-tiles t ≡ s (mod 2). 4 waves own 16
// q-rows each, SHARE the staged K/V tile. 2-phase async pipeline via
// global_load_lds (round-5: structural staging works; grid was the cap).
// Partials (unnormalized O, m, l) -> workspace; k_merge combines the 2 splits.
__global__ __launch_bounds__(256, 4) void k_attn(
    const unsigned short* __restrict__ Qb, const unsigned short* __restrict__ Kb,
    const unsigned short* __restrict__ Vt, float* __restrict__ Opart,
    float* __restrict__ mlw) {
  __shared__ unsigned short Ks[2][64 * 64];   // [key][d], swizzled, 8KB each
  __shared__ unsigned short Vs[2][64 * 64];   // [d][key], swizzled, 8KB each
  __shared__ unsigned char Pl[4][2048];       // per-wave P^T (16 q x 64 k bf16, swizzled)
  const int tid = threadIdx.x;
  const int lane = tid & 63;
  const int w = tid >> 6;
  const int l15 = lane & 15, l4 = lane >> 4;
  const int bid = blockIdx.x;
  const int s = bid & 1;                 // key-split index
  const int b2 = bid >> 1;
  const int h = b2 % NH;
  const int qt = 63 - (b2 / NH);         // heavy q-tiles dispatch first
  const int q0 = qt * 64 + w * 16;       // this wave's first q-row
  const int ntiles = qt + 1;
  const float SCL = 0.125f * 1.44269504f;  // (1/sqrt(hd)) * log2(e)

  const unsigned short* const Kh = Kb + h * HD;
  const unsigned short* const Vh = Vt + h * HD * SEQ;

  // staging: 512 chunks of 16B per matrix; chunk c: row rr=c>>3, lds slot c&7
  // holds global slot (c&7) ^ (rr&7). Linear LDS dest (wave base + lane*16).
  int srow[2], scol[2];
#pragma unroll
  for (int j = 0; j < 2; j++) {
    int c = j * 256 + tid;
    srow[j] = c >> 3;
    scol[j] = ((c & 7) ^ (srow[j] & 7)) * 8;   // element offset within 64-wide row
  }
  const int ldsoff0 = (tid & ~63) * 16;         // j=0 wave-uniform byte base
  const int ldsoff1 = 4096 + (tid & ~63) * 16;  // j=1

  // Q fragment (B-operand of swapped QK): lane holds Q[q0+l15][kc*32 + l4*8 ..+7]
  s8v aq[2];
#pragma unroll
  for (int kc = 0; kc < 2; kc++)
    aq[kc] = *reinterpret_cast<const s8v*>(&Qb[(q0 + l15) * DM + h * HD + kc * 32 + l4 * 8]);

  // LDS read base: row rr=l15(+16c2), slot g=l4 -> byte rr*128 + ((g^(rr&7))<<4)
  const int kvbase = l15 * 128 + ((l4 ^ (l15 & 7)) << 4);  // + c2*2048, ^64 for 2nd half

  // P-LDS per-lane offsets (XOR swizzle by q-row)
  unsigned char* const pw = (unsigned char*)&Pl[w][0];
  const int swz = (l15 & 7) << 4;
  const int wr_base = l15 * 128 + l4 * 8;    // + c2*32, ^ swz
  const int rd_base = l15 * 128 + l4 * 16;   // + kc2*64, ^ swz
  const int lanediff = l15 - l4 * 4;

  f32x4 Ot[4] = {};                          // Ot[dc][r] = O[q=l15][d=dc*16+l4*4+r]
  float m = -1e30f, lsum = 0.f;

  // ---- prologue: stage tile t=s into buffer 0 (if it exists) ----
  if (s < ntiles) {
    const int kb0 = s * 64;
    gload16(Kh + (kb0 + srow[0]) * DM + scol[0], (char*)Ks[0] + ldsoff0);
    gload16(Kh + (kb0 + srow[1]) * DM + scol[1], (char*)Ks[0] + ldsoff1);
    gload16(Vh + srow[0] * SEQ + kb0 + scol[0], (char*)Vs[0] + ldsoff0);
    gload16(Vh + srow[1] * SEQ + kb0 + scol[1], (char*)Vs[0] + ldsoff1);
    __asm__ volatile("s_waitcnt vmcnt(0)" ::: "memory");
  }
  __syncthreads();

  for (int t = s; t < ntiles; t += 2) {
    const int cur = ((t - s) >> 1) & 1;
    // ---- stage tile t+2 (async, no VGPR cost) ----
    if (t + 2 < ntiles) {
      const int kb2 = (t + 2) * 64;
      const int nxt = cur ^ 1;
      gload16(Kh + (kb2 + srow[0]) * DM + scol[0], (char*)Ks[nxt] + ldsoff0);
      gload16(Kh + (kb2 + srow[1]) * DM + scol[1], (char*)Ks[nxt] + ldsoff1);
      gload16(Vh + srow[0] * SEQ + kb2 + scol[0], (char*)Vs[nxt] + ldsoff0);
      gload16(Vh + srow[1] * SEQ + kb2 + scol[1], (char*)Vs[nxt] + ldsoff1);
    }
    const int kb = t * 64;
    const char* const kbuf = (const char*)Ks[cur];
    const char* const vbuf = (const char*)Vs[cur];

    // ---- swapped QK^T from LDS: key = kb + c2*16 + l4*4 + r, q = q0 + l15 ----
    float p[4][4];
#pragma unroll
    for (int c2 = 0; c2 < 4; c2++) {
      const s8v k0 = *reinterpret_cast<const s8v*>(kbuf + (c2 * 2048 + kvbase));
      const s8v k1 = *reinterpret_cast<const s8v*>(kbuf + ((c2 * 2048 + kvbase) ^ 64));
      f32x4 z = {};
      z = __builtin_amdgcn_mfma_f32_16x16x32_bf16(k0, aq[0], z, 0, 0, 0);
      z = __builtin_amdgcn_mfma_f32_16x16x32_bf16(k1, aq[1], z, 0, 0, 0);
#pragma unroll
      for (int r = 0; r < 4; r++) p[c2][r] = z[r];
    }
    // causal mask: only the diagonal tile (wave-uniform branch)
    if (kb + 63 > q0) {
      const int qml = q0 - kb + lanediff;   // mask if c2*16 + r > qml
#pragma unroll
      for (int c2 = 0; c2 < 4; c2++)
#pragma unroll
        for (int r = 0; r < 4; r++)
          p[c2][r] = (c2 * 16 + r > qml) ? -1e30f : p[c2][r];
    }
    // ---- in-lane softmax (log2 domain), 2 shuffles per tile ----
    float t0 = fmaxf(fmaxf(p[0][0], p[0][1]), fmaxf(p[0][2], p[0][3]));
    float t1 = fmaxf(fmaxf(p[1][0], p[1][1]), fmaxf(p[1][2], p[1][3]));
    float t2 = fmaxf(fmaxf(p[2][0], p[2][1]), fmaxf(p[2][2], p[2][3]));
    float t3 = fmaxf(fmaxf(p[3][0], p[3][1]), fmaxf(p[3][2], p[3][3]));
    float tm = fmaxf(fmaxf(t0, t1), fmaxf(t2, t3));
    tm = fmaxf(tm, __shfl_xor(tm, 16));
    tm = fmaxf(tm, __shfl_xor(tm, 32));
    const float tsc = tm * SCL;
    // defer-max (T13): rescale only when tile max exceeds running max by >8
    if (!__all(tsc <= m + 8.f)) {
      const float mn = fmaxf(m, tsc);
      const float al = exp2f(m - mn);
      m = mn;
      lsum *= al;
#pragma unroll
      for (int dc = 0; dc < 4; dc++)
#pragma unroll
        for (int r = 0; r < 4; r++) Ot[dc][r] *= al;
    }
    // ---- exp, pack bf16, P^T -> LDS ----
    float sacc = 0.f;
#pragma unroll
    for (int c2 = 0; c2 < 4; c2++) {
      float e0 = exp2f(fmaf(p[c2][0], SCL, -m));
      float e1 = exp2f(fmaf(p[c2][1], SCL, -m));
      float e2 = exp2f(fmaf(p[c2][2], SCL, -m));
      float e3 = exp2f(fmaf(p[c2][3], SCL, -m));
      sacc += (e0 + e1) + (e2 + e3);
      u32x2 pk;
      pk.x = cvtpk(e0, e1);
      pk.y = cvtpk(e2, e3);
      *reinterpret_cast<u32x2*>(pw + ((wr_base + c2 * 32) ^ swz)) = pk;
    }
    lsum += sacc;
    __asm__ volatile("s_waitcnt lgkmcnt(0)" ::: "memory");
    const s8v pb0 = *reinterpret_cast<const s8v*>(pw + (rd_base ^ swz));
    const s8v pb1 = *reinterpret_cast<const s8v*>(pw + ((rd_base + 64) ^ swz));
    // ---- swapped PV from LDS V^T ----
#pragma unroll
    for (int dc = 0; dc < 4; dc++) {
      const s8v v0 = *reinterpret_cast<const s8v*>(vbuf + (dc * 2048 + kvbase));
      const s8v v1 = *reinterpret_cast<const s8v*>(vbuf + ((dc * 2048 + kvbase) ^ 64));
      Ot[dc] = __builtin_amdgcn_mfma_f32_16x16x32_bf16(v0, pb0, Ot[dc], 0, 0, 0);
      Ot[dc] = __builtin_amdgcn_mfma_f32_16x16x32_bf16(v1, pb1, Ot[dc], 0, 0, 0);
    }
    // ---- next tile staged & everyone done reading cur ----
    __asm__ volatile("s_waitcnt vmcnt(0)" ::: "memory");
    __syncthreads();
  }

  // ---- publish partials: unnormalized O, (m, l) per q-row ----
  lsum += __shfl_xor(lsum, 16);
  lsum += __shfl_xor(lsum, 32);
  float* const op = Opart + (size_t)s * SEQ * DM + (q0 + l15) * DM + h * HD;
#pragma unroll
  for (int dc = 0; dc < 4; dc++)
    *reinterpret_cast<f32x4*>(op + dc * 16 + l4 * 4) = Ot[dc];
  if (l4 == 0) {
    float2* const mp = (float2*)mlw;
    mp[(s * NH + h) * SEQ + q0 + l15] = make_float2(m, lsum);
  }
}

// ---------------- merge the 2 key-split partials -> bf16 attn ----------------
__global__ __launch_bounds__(256) void k_merge(const float* __restrict__ Opart,
                                               const float* __restrict__ mlw,
                                               unsigned short* __restrict__ attn) {
  const int idx = blockIdx.x * 256 + threadIdx.x;
  const int e4 = idx * 4;                   // 4 consecutive d-elements
  const int row = e4 / DM;
  const int col = e4 - row * DM;
  const int h = col >> 6;
  const float2* mp = (const float2*)mlw;
  const float2 a = mp[h * SEQ + row];             // split 0: (m, l)
  const float2 b = mp[(NH + h) * SEQ + row];      // split 1
  const float ms = fmaxf(a.x, b.x);
  const float w0 = exp2f(a.x - ms), w1 = exp2f(b.x - ms);
  const float rl = 1.f / (w0 * a.y + w1 * b.y);
  const float4 o0 = *reinterpret_cast<const float4*>(Opart + e4);
  const float4 o1 = *reinterpret_cast<const float4*>(Opart + (size_t)SEQ * DM + e4);
  u16x4 pk;
  pk.x = f2bf((w0 * o0.x + w1 * o1.x) * rl);
  pk.y = f2bf((w0 * o0.y + w1 * o1.y) * rl);
  pk.z = f2bf((w0 * o0.z + w1 * o1.z) * rl);
  pk.w = f2bf((w0 * o0.w + w1 * o1.w) * rl);
  *reinterpret_cast<u16x4*>(attn + e4) = pk;
}

extern "C" void kernel_launch(void* const* d_in, const int* in_sizes, int n_in,
                              void* d_out, int out_size, void* d_ws, size_t ws_size,
                              hipStream_t stream) {
  (void)in_sizes; (void)n_in; (void)out_size; (void)ws_size;
  const float* tokens = (const float*)d_in[0];
  const float* wqkv  = (const float*)d_in[2];
  const float* bqkv  = (const float*)d_in[3];
  const float* wproj = (const float*)d_in[4];
  const float* bproj = (const float*)d_in[5];
  float* out = (float*)d_out;

  unsigned short* tok    = (unsigned short*)d_ws;       // [4096][768]
  unsigned short* wqkvT  = tok + 4096 * 768;            // [2304][768]
  unsigned short* wprojT = wqkvT + 2304 * 768;          // [768][768]
  unsigned short* Qb     = wprojT + 768 * 768;          // [4096][768]
  unsigned short* Kb     = Qb + 4096 * 768;             // [4096][768]
  unsigned short* Vt     = Kb + 4096 * 768;             // [768][4096]
  unsigned short* attn   = Vt + 768 * 4096;             // [4096][768]
  float* Opart = (float*)(attn + 4096 * 768);           // 2 x [4096][768] f32
  float* mlw   = Opart + 2 * 4096 * 768;                // 2 x 12 x 4096 float2

  k_cast<<<3072, 256, 0, stream>>>(tokens, tok);
  k_transpose_cast<<<dim3(24, 72), 256, 0, stream>>>(wqkv, wqkvT, 768, 2304);
  k_transpose_cast<<<dim3(24, 24), 256, 0, stream>>>(wproj, wprojT, 768, 768);
  k_gemm<0><<<dim3(32, 18), 256, 0, stream>>>(tok, wqkvT, bqkv, Qb, Kb, Vt, nullptr);
  k_attn<<<1536, 256, 0, stream>>>(Qb, Kb, Vt, Opart, mlw);
  k_merge<<<3072, 256, 0, stream>>>(Opart, mlw, attn);
  k_gemm<1><<<dim3(32, 6), 256, 0, stream>>>(attn, wprojT, bproj, nullptr, nullptr, nullptr, out);
}